// Round 13
// baseline (71.064 us; speedup 1.0000x reference)
//
#include <hip/hip_runtime.h>

// Involution1d fused v6: B=16, CH=256, DIM=4096, G=16, K=7, PAD=3,
// hid=64, K*G=112.  128-thread blocks, TLC=32, LDS 26.9 KiB -> 5 blocks/CU,
// 2048 de-synced block streams keep HBM busy.
// stage full x tile f16 (+/-3 halo, 1 barrier) -> MFMA kerngen (hs/ks overlay)
// -> involution from LDS -> out.  x read once, out written once.
#define BB   16
#define CHN  256
#define DIMN 4096
#define KK   7
#define PADK 3
#define HID  64
#define KGN  112
#define TLC  32        // columns (locations) per block tile
#define XSD  19        // xs row stride in dw (38 halves: 3 halo + 32 + 3 halo)
#define XSH  38        // xs row stride in halves
#define HSTH 38        // hs row stride in halves
#define KSTD 36        // ks row stride in dw (mult of 4 -> aligned uint4)
#define BN_EPS 1e-5f

typedef __fp16 half2_t __attribute__((ext_vector_type(2)));
typedef __fp16 half8   __attribute__((ext_vector_type(8)));
typedef float  f32x4   __attribute__((ext_vector_type(4)));

union U32H2 { unsigned int u; half2_t h; };

static __device__ __forceinline__ unsigned int packf(float a, float b) {
    U32H2 t; t.h = __builtin_amdgcn_cvt_pkrtz(a, b); return t.u;
}
static __device__ __forceinline__ half2_t ash2(unsigned int u) { U32H2 t; t.u = u; return t.h; }
static __device__ __forceinline__ __fp16 u16h(unsigned short u) {
    return __builtin_bit_cast(__fp16, u);
}
static __device__ __forceinline__ unsigned short hu16(__fp16 h) {
    return __builtin_bit_cast(unsigned short, h);
}

// ---------------------------------------------------------------------------
// Convert w1 [64][256] and w2 [112][64] to f16 (layout unchanged); BN affine.
__global__ __launch_bounds__(256) void setup_k(
    const float* __restrict__ w1, const float* __restrict__ w2,
    const float* __restrict__ bn_gamma, const float* __restrict__ bn_beta,
    const float* __restrict__ bn_mean,  const float* __restrict__ bn_var,
    __fp16* __restrict__ w1f, __fp16* __restrict__ w2f,
    float* __restrict__ scb, float* __restrict__ shb) {
    int t = blockIdx.x * 256 + threadIdx.x;   // grid covers 16384
    if (t < HID * CHN) w1f[t] = (__fp16)w1[t];
    if (t < KGN * HID) w2f[t] = (__fp16)w2[t];
    if (t < HID) {
        float s = bn_gamma[t] * rsqrtf(bn_var[t] + BN_EPS);
        scb[t] = s;
        shb[t] = bn_beta[t] - bn_mean[t] * s;
    }
}

// ---------------------------------------------------------------------------
// kern extraction from row-pair-packed uint4 quads; OFF = g&1.
template <int OFF>
static __device__ __forceinline__ void extract_kv(const uint4 q[4], float kv[KK][4]) {
#pragma unroll
    for (int k = 0; k < KK; ++k) {
        const int kk = k + OFF;
        const int i  = kk >> 1;
        const int h  = kk & 1;
#pragma unroll
        for (int j = 0; j < 4; ++j) {
            unsigned int u = (&q[i].x)[j];
            half2_t hh = ash2(u);
            kv[k][j] = h ? (float)hh[1] : (float)hh[0];
        }
    }
}

// ---------------------------------------------------------------------------
// Fused kernel.  Block = (b, 32-col tile), 2 waves, 5 blocks/CU.
// xs row (halves): [0..2] left halo, [3..34] cols l0..l0+31, [35..37] right halo.
// Phases 1/2: wave w owns cols [16w,16w+16) (colL in [0,32)).
// Involution: wave w owns g in {8w..8w+7}; lane -> col quad (l&7), ch (l>>3).
// Fragment maps (16x16x32): A[m][k]: m=lane&15, k=8*((lane>>4)&3)+j;
// B[k][n]: n=lane&15; D[m][n]: n=lane&15, m=4*((lane>>4)&3)+reg.
__global__ __launch_bounds__(128, 5) void fused_k(
    const float* __restrict__ x,
    const __fp16* __restrict__ w1f,
    const float* __restrict__ b1,
    const float* __restrict__ scb, const float* __restrict__ shb,
    const __fp16* __restrict__ w2f,
    const float* __restrict__ b2,
    float* __restrict__ out) {
    __shared__ unsigned int xs[CHN * XSD];   // 19456 B (f16 x tile + halo)
    __shared__ unsigned int un[56 * KSTD];   // 8064 B (hs then ks, overlaid)

    unsigned short* xs16 = (unsigned short*)xs;
    unsigned short* hs16 = (unsigned short*)un;
    unsigned int*   ks   = un;

    const int t    = threadIdx.x;          // 0..127
    const int lane = t & 63;
    const int w    = t >> 6;               // wave 0..1
    const int lr   = t & 15;
    const int lg   = (t >> 4) & 3;
    const int b    = blockIdx.x >> 7;
    const int l0   = (blockIdx.x & 127) * TLC;
    const int colL = 16 * w + lr;          // wave's column (0..31)

    // ---- Stage full x tile -> LDS f16 (one shot, 18 loads/thread) ----
    {
        const int colq = t & 7;            // col quad 0..7
        const int chl  = t >> 3;           // 0..15
        const float* xg = x + ((size_t)b * CHN + chl) * DIMN + l0 + 4 * colq;
        float4 v[16];
#pragma unroll
        for (int i = 0; i < 16; ++i)
            v[i] = *(const float4*)(xg + (size_t)(16 * i) * DIMN);
#pragma unroll
        for (int i = 0; i < 16; ++i) {
            unsigned short* rp = xs16 + (chl + 16 * i) * XSH + 4 * colq + 3;
            rp[0] = hu16((__fp16)v[i].x);
            *(unsigned int*)(rp + 1) = packf(v[i].y, v[i].z);
            rp[3] = hu16((__fp16)v[i].w);
        }
        // halo: thread covers rows t and t+128, both sides
#pragma unroll
        for (int rr = 0; rr < 2; ++rr) {
            const int row = t + 128 * rr;
            const float* xrow = x + ((size_t)b * CHN + row) * DIMN;
            float4 lv = (l0 > 0) ? *(const float4*)(xrow + l0 - 4)
                                 : make_float4(0.f, 0.f, 0.f, 0.f);
            float4 rv = (l0 + TLC < DIMN) ? *(const float4*)(xrow + l0 + TLC)
                                          : make_float4(0.f, 0.f, 0.f, 0.f);
            unsigned short* hp = xs16 + row * XSH;
            hp[0]  = hu16((__fp16)lv.y);
            hp[1]  = hu16((__fp16)lv.z);
            hp[2]  = hu16((__fp16)lv.w);
            hp[35] = hu16((__fp16)rv.x);
            hp[36] = hu16((__fp16)rv.y);
            hp[37] = hu16((__fp16)rv.z);
        }
    }
    __syncthreads();

    // ---- Phase 1: h = w1 . x  (4 o-frags x 8 K-steps) ----
    f32x4 acc[4];
#pragma unroll
    for (int of = 0; of < 4; ++of) acc[of] = (f32x4){0.f, 0.f, 0.f, 0.f};

#pragma unroll
    for (int p = 0; p < 8; ++p) {
        half8 bf;
#pragma unroll
        for (int j = 0; j < 8; ++j)
            bf[j] = u16h(xs16[(32 * p + 8 * lg + j) * XSH + colL + 3]);
#pragma unroll
        for (int of = 0; of < 4; ++of) {
            half8 af = *(const half8*)(w1f + (16 * of + lr) * CHN + 32 * p + 8 * lg);
            acc[of] = __builtin_amdgcn_mfma_f32_16x16x32_f16(af, bf, acc[of], 0, 0, 0);
        }
    }

    // ---- bias + relu + BN; h -> hs (wave-private cols, same-wave consumer)
#pragma unroll
    for (int of = 0; of < 4; ++of) {
#pragma unroll
        for (int r = 0; r < 4; ++r) {
            const int o = 16 * of + 4 * lg + r;
            float hv = fmaxf(acc[of][r] + b1[o], 0.f) * scb[o] + shb[o];
            hs16[o * HSTH + colL] = hu16((__fp16)hv);
        }
    }

    // ---- Phase 2: kern = w2 . h  (7 r-frags x 2 K-steps) ----
    f32x4 acc2[7];
#pragma unroll
    for (int rf = 0; rf < 7; ++rf) acc2[rf] = (f32x4){0.f, 0.f, 0.f, 0.f};

#pragma unroll
    for (int kx = 0; kx < 2; ++kx) {
        half8 bf;
#pragma unroll
        for (int j = 0; j < 8; ++j)
            bf[j] = u16h(hs16[(32 * kx + 8 * lg + j) * HSTH + colL]);
#pragma unroll
        for (int rf = 0; rf < 7; ++rf) {
            half8 af = *(const half8*)(w2f + (16 * rf + lr) * HID + 32 * kx + 8 * lg);
            acc2[rf] = __builtin_amdgcn_mfma_f32_16x16x32_f16(af, bf, acc2[rf], 0, 0, 0);
        }
    }

    // all hs reads done; barrier before overlaying ks onto the union buffer
    __syncthreads();

    // ---- bias + row-pair pack -> ks (overlaid on hs region)
#pragma unroll
    for (int rf = 0; rf < 7; ++rf) {
#pragma unroll
        for (int p = 0; p < 2; ++p) {
            const int r0 = 16 * rf + 4 * lg + 2 * p;
            float k0 = acc2[rf][2 * p + 0] + b2[r0 + 0];
            float k1 = acc2[rf][2 * p + 1] + b2[r0 + 1];
            ks[(r0 >> 1) * KSTD + colL] = packf(k0, k1);
        }
    }
    __syncthreads();

    // ---- Involution: wave w -> groups {8w..8w+7}; taps from LDS f16 ----
    const int q4    = lane & 7;
    const int hi    = lane >> 3;           // 0..7
    const int cbase = 4 * q4;              // relative col of this lane's quad

#pragma unroll
    for (int gi = 0; gi < 8; ++gi) {
        const int g   = 8 * w + gi;        // parity = gi & 1 (8w even)
        const int rpb = (7 * g) >> 1;
        uint4 qq[4];
#pragma unroll
        for (int ii = 0; ii < 4; ++ii)
            qq[ii] = *(const uint4*)(ks + (rpb + ii) * KSTD + cbase);
        float kv[KK][4];
        if ((gi & 1) == 0) extract_kv<0>(qq, kv);
        else               extract_kv<1>(qq, kv);

#pragma unroll
        for (int i2 = 0; i2 < 2; ++i2) {
            const int ch = 16 * g + 8 * i2 + hi;
            const unsigned int* xr = xs + ch * XSD + (cbase >> 1);
            unsigned int uu[5];
#pragma unroll
            for (int j = 0; j < 5; ++j) uu[j] = xr[j];
            // halves cbase..cbase+9; out col cbase+j taps xv[j..j+6]
            float xv[10];
#pragma unroll
            for (int r = 0; r < 10; ++r) {
                half2_t hh = ash2(uu[r >> 1]);
                xv[r] = (r & 1) ? (float)hh[1] : (float)hh[0];
            }
            float o0 = 0.f, o1 = 0.f, o2 = 0.f, o3 = 0.f;
#pragma unroll
            for (int k = 0; k < KK; ++k) {
                o0 = fmaf(kv[k][0], xv[k + 0], o0);
                o1 = fmaf(kv[k][1], xv[k + 1], o1);
                o2 = fmaf(kv[k][2], xv[k + 2], o2);
                o3 = fmaf(kv[k][3], xv[k + 3], o3);
            }
            *(float4*)(out + ((size_t)b * CHN + ch) * DIMN + l0 + cbase) =
                make_float4(o0, o1, o2, o3);
        }
    }
}

// ---------------------------------------------------------------------------
extern "C" void kernel_launch(void* const* d_in, const int* in_sizes, int n_in,
                              void* d_out, int out_size, void* d_ws, size_t ws_size,
                              hipStream_t stream) {
    (void)in_sizes; (void)n_in; (void)out_size; (void)ws_size;

    const float* x        = (const float*)d_in[0];
    const float* w1       = (const float*)d_in[1];
    const float* b1       = (const float*)d_in[2];
    const float* bn_gamma = (const float*)d_in[3];
    const float* bn_beta  = (const float*)d_in[4];
    const float* bn_mean  = (const float*)d_in[5];
    const float* bn_var   = (const float*)d_in[6];
    const float* w2       = (const float*)d_in[7];
    const float* b2       = (const float*)d_in[8];
    float*       out      = (float*)d_out;

    __fp16* w1f = (__fp16*)d_ws;                 // 16384 f16
    __fp16* w2f = w1f + HID * CHN;               // 7168 f16
    float*  scb = (float*)(w2f + KGN * HID);     // 64
    float*  shb = scb + HID;                     // 64

    setup_k<<<(HID * CHN + 255) / 256, 256, 0, stream>>>(
        w1, w2, bn_gamma, bn_beta, bn_mean, bn_var, w1f, w2f, scb, shb);
    fused_k<<<BB * (DIMN / TLC), 128, 0, stream>>>(
        x, w1f, b1, scb, shb, w2f, b2, out);
}

// Round 14
// 66.371 us; speedup vs baseline: 1.0707x; 1.0707x over previous
//
#include <hip/hip_runtime.h>

// Involution1d fused v7: B=16, CH=256, DIM=4096, G=16, K=7, PAD=3,
// hid=64, K*G=112.  TLC=256: every global stream is 1 KB-contiguous per
// wave-instruction.  grid 256 = 1 block/CU.  Panel-streamed x (f16, dbuf,
// overlaid on ks region) -> MFMA kerngen -> ks LDS -> involution (x taps
// re-read from global f32, out 1 KB stores).  LDS 91.8 KiB.
#define BB   16
#define CHN  256
#define DIMN 4096
#define KK   7
#define HID  64
#define KGN  112
#define TLC  256
#define NPAN 8
#define PCH  32
#define PSTD 131       // panel/hs row stride in dw (262 halves, odd)
#define KSTD 260       // ks row stride in dw (mult of 4)
#define HS_DW (HID * PSTD)   // 8384 dw
#define KS_DW (56 * KSTD)    // 14560 dw
#define BN_EPS 1e-5f

typedef __fp16 half2_t __attribute__((ext_vector_type(2)));
typedef __fp16 half8   __attribute__((ext_vector_type(8)));
typedef float  f32x4   __attribute__((ext_vector_type(4)));

union U32H2 { unsigned int u; half2_t h; };

static __device__ __forceinline__ unsigned int packf(float a, float b) {
    U32H2 t; t.h = __builtin_amdgcn_cvt_pkrtz(a, b); return t.u;
}
static __device__ __forceinline__ half2_t ash2(unsigned int u) { U32H2 t; t.u = u; return t.h; }
static __device__ __forceinline__ __fp16 u16h(unsigned short u) {
    return __builtin_bit_cast(__fp16, u);
}

// ---------------------------------------------------------------------------
__global__ __launch_bounds__(256) void setup_k(
    const float* __restrict__ w1, const float* __restrict__ w2,
    const float* __restrict__ bn_gamma, const float* __restrict__ bn_beta,
    const float* __restrict__ bn_mean,  const float* __restrict__ bn_var,
    __fp16* __restrict__ w1f, __fp16* __restrict__ w2f,
    float* __restrict__ scb, float* __restrict__ shb) {
    int t = blockIdx.x * 256 + threadIdx.x;   // grid covers 16384
    if (t < HID * CHN) w1f[t] = (__fp16)w1[t];
    if (t < KGN * HID) w2f[t] = (__fp16)w2[t];
    if (t < HID) {
        float s = bn_gamma[t] * rsqrtf(bn_var[t] + BN_EPS);
        scb[t] = s;
        shb[t] = bn_beta[t] - bn_mean[t] * s;
    }
}

// ---------------------------------------------------------------------------
// kern extraction from row-pair-packed uint4 quads; OFF = g&1.
template <int OFF>
static __device__ __forceinline__ void extract_kv(const uint4 q[4], float kv[KK][4]) {
#pragma unroll
    for (int k = 0; k < KK; ++k) {
        const int kk = k + OFF;
        const int i  = kk >> 1;
        const int h  = kk & 1;
#pragma unroll
        for (int j = 0; j < 4; ++j) {
            unsigned int u = (&q[i].x)[j];
            half2_t hh = ash2(u);
            kv[k][j] = h ? (float)hh[1] : (float)hh[0];
        }
    }
}

// ---------------------------------------------------------------------------
// Fused kernel.  Block = (b, 256-col tile), 4 waves, grid 256 (1/CU).
// Phases 1/2: wave w owns cols [64w, 64w+64) (4 col-frags).
// Involution: wave w owns g {4w..4w+3}; lane owns col quad 4*lane (0..255).
// Fragment maps (16x16x32): A[m][k]: m=lane&15, k=8*((lane>>4)&3)+j;
// B[k][n]: n=lane&15; D[m][n]: n=lane&15, m=4*((lane>>4)&3)+reg.
__global__ __launch_bounds__(256, 1) void fused_k(
    const float* __restrict__ x,
    const __fp16* __restrict__ w1f,
    const float* __restrict__ b1,
    const float* __restrict__ scb, const float* __restrict__ shb,
    const __fp16* __restrict__ w2f,
    const float* __restrict__ b2,
    float* __restrict__ out) {
    __shared__ unsigned int lds[HS_DW + KS_DW];   // 91.8 KiB
    unsigned short* hs16 = (unsigned short*)lds;  // [64][262 halves]
    unsigned int*   ks   = lds + HS_DW;           // [56][260 dw]
    unsigned int*   pan0 = ks;                    // panels overlay ks region
    unsigned int*   pan1 = ks + PCH * PSTD;

    const int t    = threadIdx.x;          // 0..255
    const int lane = t & 63;
    const int w    = t >> 6;               // wave 0..3
    const int lr   = t & 15;
    const int lg   = (t >> 4) & 3;
    const int b    = blockIdx.x >> 4;
    const int l0   = (blockIdx.x & 15) * TLC;

    // staging ids: cq = col quad (0..63) -> wave-instr covers one full 1 KB row
    const int cq  = t & 63;
    const int rr0 = t >> 6;                // 0..3
    const float* xg = x + (size_t)b * CHN * DIMN + l0 + 4 * cq;

    float4 v[8];
    // ---- prologue: stage panel 0
#pragma unroll
    for (int i = 0; i < 8; ++i)
        v[i] = *(const float4*)(xg + (size_t)(rr0 + 4 * i) * DIMN);
#pragma unroll
    for (int i = 0; i < 8; ++i) {
        uint2 u;
        u.x = packf(v[i].x, v[i].y);
        u.y = packf(v[i].z, v[i].w);
        *(uint2*)&pan0[(rr0 + 4 * i) * PSTD + 2 * cq] = u;
    }
    __syncthreads();

    // ---- Phase 1: h = w1 . x  (4 o-frags x 4 col-frags x 8 panels) ----
    f32x4 acc[4][4];
#pragma unroll
    for (int of = 0; of < 4; ++of)
#pragma unroll
        for (int cf = 0; cf < 4; ++cf) acc[of][cf] = (f32x4){0.f, 0.f, 0.f, 0.f};

    for (int p = 0; p < NPAN; ++p) {
        if (p + 1 < NPAN) {
#pragma unroll
            for (int i = 0; i < 8; ++i)
                v[i] = *(const float4*)(xg + (size_t)(32 * (p + 1) + rr0 + 4 * i) * DIMN);
        }
        const unsigned short* pb = (const unsigned short*)((p & 1) ? pan1 : pan0);
        half8 af[4];
#pragma unroll
        for (int of = 0; of < 4; ++of)
            af[of] = *(const half8*)(w1f + (16 * of + lr) * CHN + 32 * p + 8 * lg);
#pragma unroll
        for (int cf = 0; cf < 4; ++cf) {
            half8 bf;
#pragma unroll
            for (int j = 0; j < 8; ++j)
                bf[j] = u16h(pb[(8 * lg + j) * (2 * PSTD) + 64 * w + 16 * cf + lr]);
#pragma unroll
            for (int of = 0; of < 4; ++of)
                acc[of][cf] = __builtin_amdgcn_mfma_f32_16x16x32_f16(af[of], bf, acc[of][cf], 0, 0, 0);
        }
        if (p + 1 < NPAN) {
            __syncthreads();
            unsigned int* pw = ((p + 1) & 1) ? pan1 : pan0;
#pragma unroll
            for (int i = 0; i < 8; ++i) {
                uint2 u;
                u.x = packf(v[i].x, v[i].y);
                u.y = packf(v[i].z, v[i].w);
                *(uint2*)&pw[(rr0 + 4 * i) * PSTD + 2 * cq] = u;
            }
            __syncthreads();
        }
    }
    __syncthreads();   // all panel reads done; ks region reusable

    // ---- bias + relu + BN; h -> hs (wave-private cols, same-wave consumer)
#pragma unroll
    for (int of = 0; of < 4; ++of)
#pragma unroll
        for (int r = 0; r < 4; ++r) {
            const int o  = 16 * of + 4 * lg + r;
            const float bo = b1[o], sc = scb[o], sh = shb[o];
#pragma unroll
            for (int cf = 0; cf < 4; ++cf) {
                float hv = fmaxf(acc[of][cf][r] + bo, 0.f) * sc + sh;
                hs16[o * (2 * PSTD) + 64 * w + 16 * cf + lr] =
                    __builtin_bit_cast(unsigned short, (__fp16)hv);
            }
        }

    // ---- Phase 2: kern = w2 . h, two col-frag halves (VGPR control) ----
#pragma unroll
    for (int ch2 = 0; ch2 < 2; ++ch2) {
        f32x4 acc2[7][2];
#pragma unroll
        for (int rf = 0; rf < 7; ++rf)
#pragma unroll
            for (int cc = 0; cc < 2; ++cc) acc2[rf][cc] = (f32x4){0.f, 0.f, 0.f, 0.f};

#pragma unroll
        for (int kx = 0; kx < 2; ++kx) {
            half8 bf[2];
#pragma unroll
            for (int cc = 0; cc < 2; ++cc) {
                const int col = 64 * w + 16 * (2 * ch2 + cc) + lr;
#pragma unroll
                for (int j = 0; j < 8; ++j)
                    bf[cc][j] = u16h(hs16[(32 * kx + 8 * lg + j) * (2 * PSTD) + col]);
            }
#pragma unroll
            for (int rf = 0; rf < 7; ++rf) {
                half8 af2 = *(const half8*)(w2f + (16 * rf + lr) * HID + 32 * kx + 8 * lg);
                acc2[rf][0] = __builtin_amdgcn_mfma_f32_16x16x32_f16(af2, bf[0], acc2[rf][0], 0, 0, 0);
                acc2[rf][1] = __builtin_amdgcn_mfma_f32_16x16x32_f16(af2, bf[1], acc2[rf][1], 0, 0, 0);
            }
        }
        // bias + row-pair pack -> ks
#pragma unroll
        for (int rf = 0; rf < 7; ++rf)
#pragma unroll
            for (int p2 = 0; p2 < 2; ++p2) {
                const int r0 = 16 * rf + 4 * lg + 2 * p2;
                const float ba = b2[r0], bb2 = b2[r0 + 1];
#pragma unroll
                for (int cc = 0; cc < 2; ++cc) {
                    const int col = 64 * w + 16 * (2 * ch2 + cc) + lr;
                    ks[(r0 >> 1) * KSTD + col] =
                        packf(acc2[rf][cc][2 * p2 + 0] + ba, acc2[rf][cc][2 * p2 + 1] + bb2);
                }
            }
    }
    __syncthreads();

    // ---- Involution: wave w -> g {4w..4w+3}; lane -> col quad 4*lane ----
    const int cb   = 4 * lane;             // 0..252
    const int col0 = l0 + cb;

#pragma unroll
    for (int gi = 0; gi < 4; ++gi) {
        const int g   = 4 * w + gi;        // parity = gi & 1 (4w even)
        const int rpb = (7 * g) >> 1;
        uint4 qq[4];
#pragma unroll
        for (int ii = 0; ii < 4; ++ii)
            qq[ii] = *(const uint4*)(ks + (rpb + ii) * KSTD + cb);
        float kv[KK][4];
        if ((gi & 1) == 0) extract_kv<0>(qq, kv);
        else               extract_kv<1>(qq, kv);

#pragma unroll 4
        for (int i2 = 0; i2 < 16; ++i2) {
            const int ch = 16 * g + i2;
            const float* xrow = x + ((size_t)b * CHN + ch) * DIMN;
            float4 fa = (col0 > 0) ? *(const float4*)(xrow + col0 - 4)
                                   : make_float4(0.f, 0.f, 0.f, 0.f);
            float4 fb = *(const float4*)(xrow + col0);
            float4 fc = (col0 + 4 < DIMN) ? *(const float4*)(xrow + col0 + 4)
                                          : make_float4(0.f, 0.f, 0.f, 0.f);

            float xr[10] = { fa.y, fa.z, fa.w, fb.x, fb.y, fb.z, fb.w, fc.x, fc.y, fc.z };

            float o0 = 0.f, o1 = 0.f, o2 = 0.f, o3 = 0.f;
#pragma unroll
            for (int k = 0; k < KK; ++k) {
                o0 = fmaf(kv[k][0], xr[k + 0], o0);
                o1 = fmaf(kv[k][1], xr[k + 1], o1);
                o2 = fmaf(kv[k][2], xr[k + 2], o2);
                o3 = fmaf(kv[k][3], xr[k + 3], o3);
            }
            *(float4*)(out + ((size_t)b * CHN + ch) * DIMN + col0) =
                make_float4(o0, o1, o2, o3);
        }
    }
}

// ---------------------------------------------------------------------------
extern "C" void kernel_launch(void* const* d_in, const int* in_sizes, int n_in,
                              void* d_out, int out_size, void* d_ws, size_t ws_size,
                              hipStream_t stream) {
    (void)in_sizes; (void)n_in; (void)out_size; (void)ws_size;

    const float* x        = (const float*)d_in[0];
    const float* w1       = (const float*)d_in[1];
    const float* b1       = (const float*)d_in[2];
    const float* bn_gamma = (const float*)d_in[3];
    const float* bn_beta  = (const float*)d_in[4];
    const float* bn_mean  = (const float*)d_in[5];
    const float* bn_var   = (const float*)d_in[6];
    const float* w2       = (const float*)d_in[7];
    const float* b2       = (const float*)d_in[8];
    float*       out      = (float*)d_out;

    __fp16* w1f = (__fp16*)d_ws;                 // 16384 f16
    __fp16* w2f = w1f + HID * CHN;               // 7168 f16
    float*  scb = (float*)(w2f + KGN * HID);     // 64
    float*  shb = scb + HID;                     // 64

    setup_k<<<(HID * CHN + 255) / 256, 256, 0, stream>>>(
        w1, w2, bn_gamma, bn_beta, bn_mean, bn_var, w1f, w2f, scb, shb);
    fused_k<<<BB * (DIMN / TLC), 256, 0, stream>>>(
        x, w1f, b1, scb, shb, w2f, b2, out);
}